// Round 1
// baseline (181.868 us; speedup 1.0000x reference)
//
#include <hip/hip_runtime.h>
#include <hip/hip_bf16.h>

typedef __attribute__((ext_vector_type(8))) short bf16x8;
typedef __attribute__((ext_vector_type(4))) float f32x4;

#define BM 128
#define BN 128
#define BK 32

// ---------------- cast kernels ----------------

__global__ __launch_bounds__(256) void cast_bf16_kernel(
    const float* __restrict__ in, __hip_bfloat16* __restrict__ out, int n4) {
  int i = blockIdx.x * 256 + threadIdx.x;
  if (i >= n4) return;
  const float4 v = reinterpret_cast<const float4*>(in)[i];
  __hip_bfloat16* o = out + (size_t)i * 4;
  o[0] = __float2bfloat16(v.x);
  o[1] = __float2bfloat16(v.y);
  o[2] = __float2bfloat16(v.z);
  o[3] = __float2bfloat16(v.w);
}

// in[R][C] (fp32) -> out[C][R] (bf16)   (write-coalesced)
__global__ __launch_bounds__(256) void transpose_cast_kernel(
    const float* __restrict__ in, __hip_bfloat16* __restrict__ out, int R, int C) {
  int idx = blockIdx.x * 256 + threadIdx.x;
  if (idx >= R * C) return;
  int r = idx % R;
  int c = idx / R;
  out[(size_t)c * R + r] = __float2bfloat16(in[(size_t)r * C + c]);
}

// ---------------- bf16 MFMA GEMM:  C[M,N] = A[M,K] @ BT[N,K]^T (+bias) ----------------

template <int OUT_BF16, int HAS_BIAS>
__global__ __launch_bounds__(256) void gemm_bt(
    const __hip_bfloat16* __restrict__ A,   // [M][K] row-major bf16
    const __hip_bfloat16* __restrict__ BT,  // [N][K] row-major bf16 (i.e. B transposed)
    void* __restrict__ Cout,                // [M][N] bf16 or fp32
    const float* __restrict__ bias,         // [N] fp32 (if HAS_BIAS)
    int M, int N, int K) {
  __shared__ __hip_bfloat16 As[BM * BK];  // 8 KB, linear row-major [128][32]
  __shared__ __hip_bfloat16 Bs[BN * BK];  // 8 KB, linear row-major [128][32]

  const int tid = threadIdx.x;
  const int lane = tid & 63;
  const int wid = tid >> 6;
  const int row0 = blockIdx.y * BM;
  const int col0 = blockIdx.x * BN;
  const int wrow = (wid >> 1) * 64;  // wave's 64x64 sub-tile
  const int wcol = (wid & 1) * 64;
  const int r15 = lane & 15;
  const int kb = lane >> 4;  // 0..3 -> k-group of 8

  f32x4 acc[4][4] = {};

  for (int k0 = 0; k0 < K; k0 += BK) {
#pragma unroll
    for (int i = 0; i < 2; ++i) {
      // chunk id c in [0,512): 8 bf16 (16B) per chunk; row = c/4, kcol = (c%4)*8
      int c = wid * 128 + i * 64 + lane;
      int trow = c >> 2;
      int tcol = (c & 3) * 8;
      const __hip_bfloat16* ga = A + (size_t)(row0 + trow) * K + k0 + tcol;
      const __hip_bfloat16* gb = BT + (size_t)(col0 + trow) * K + k0 + tcol;
      // LDS dest is wave-uniform base + lane*16 (linear layout matches chunk order)
      __builtin_amdgcn_global_load_lds(
          (const __attribute__((address_space(1))) void*)ga,
          (__attribute__((address_space(3))) void*)(As + (size_t)(wid * 128 + i * 64) * 8),
          16, 0, 0);
      __builtin_amdgcn_global_load_lds(
          (const __attribute__((address_space(1))) void*)gb,
          (__attribute__((address_space(3))) void*)(Bs + (size_t)(wid * 128 + i * 64) * 8),
          16, 0, 0);
    }
    __syncthreads();

    const bf16x8* Av = reinterpret_cast<const bf16x8*>(As);
    const bf16x8* Bv = reinterpret_cast<const bf16x8*>(Bs);
    bf16x8 af[4], bfr[4];
#pragma unroll
    for (int m = 0; m < 4; ++m) af[m] = Av[(wrow + m * 16 + r15) * 4 + kb];
#pragma unroll
    for (int n = 0; n < 4; ++n) bfr[n] = Bv[(wcol + n * 16 + r15) * 4 + kb];
#pragma unroll
    for (int m = 0; m < 4; ++m)
#pragma unroll
      for (int n = 0; n < 4; ++n)
        acc[m][n] = __builtin_amdgcn_mfma_f32_16x16x32_bf16(af[m], bfr[n], acc[m][n], 0, 0, 0);
    __syncthreads();
  }

  // epilogue: D row = (lane>>4)*4 + reg, col = lane&15 within each 16x16 tile
  const int orow_base = row0 + wrow + (lane >> 4) * 4;
#pragma unroll
  for (int m = 0; m < 4; ++m) {
#pragma unroll
    for (int r = 0; r < 4; ++r) {
      int row = orow_base + m * 16 + r;
#pragma unroll
      for (int n = 0; n < 4; ++n) {
        int col = col0 + wcol + n * 16 + r15;
        float v = acc[m][n][r];
        if (HAS_BIAS) v += bias[col];
        if (OUT_BF16)
          ((__hip_bfloat16*)Cout)[(size_t)row * N + col] = __float2bfloat16(v);
        else
          ((float*)Cout)[(size_t)row * N + col] = v;
      }
    }
  }
}

// ---------------- banded local attention ----------------
// qkv: [B*N][1536] bf16 (q at +0, k at +512, v at +1024; per-head offset h*64)
// att: [B*N][512] bf16
// one wave per (b,h,i); lane = head dim
__global__ __launch_bounds__(256) void local_attn_kernel(
    const __hip_bfloat16* __restrict__ qkv, __hip_bfloat16* __restrict__ att) {
  const int N = 2048;
  int unit = blockIdx.x * 4 + (threadIdx.x >> 6);
  int lane = threadIdx.x & 63;
  int b = unit >> 14;        // H*N = 16384
  int rem = unit & 16383;
  int h = rem >> 11;
  int i = rem & 2047;

  const size_t rowq = ((size_t)(b * N + i)) * 1536 + h * 64 + lane;
  float qd = __bfloat162float(qkv[rowq]) * 0.125f;  // scale = hd^-0.5 folded into q

  float s[17];
#pragma unroll
  for (int t = 0; t < 17; ++t) {
    int j = i - 8 + t;
    float val = -1e30f;
    if (j >= 0 && j < N) {  // wave-uniform branch
      float kd = __bfloat162float(qkv[((size_t)(b * N + j)) * 1536 + 512 + h * 64 + lane]);
      float p = qd * kd;
#pragma unroll
      for (int off = 32; off; off >>= 1) p += __shfl_xor(p, off, 64);
      val = p;
    }
    s[t] = val;
  }

  float mx = -1e30f;
#pragma unroll
  for (int t = 0; t < 17; ++t) mx = fmaxf(mx, s[t]);
  float den = 0.f;
#pragma unroll
  for (int t = 0; t < 17; ++t) {
    s[t] = __expf(s[t] - mx);
    den += s[t];
  }
  float inv = 1.0f / den;

  float o = 0.f;
#pragma unroll
  for (int t = 0; t < 17; ++t) {
    int j = i - 8 + t;
    if (j >= 0 && j < N) {
      float vd = __bfloat162float(qkv[((size_t)(b * N + j)) * 1536 + 1024 + h * 64 + lane]);
      o += s[t] * vd;
    }
  }
  att[((size_t)(b * N + i)) * 512 + h * 64 + lane] = __float2bfloat16(o * inv);
}

// ---------------- launch ----------------

extern "C" void kernel_launch(void* const* d_in, const int* in_sizes, int n_in,
                              void* d_out, int out_size, void* d_ws, size_t ws_size,
                              hipStream_t stream) {
  const float* x = (const float*)d_in[0];      // [4,2048,512]
  const float* Wqkv = (const float*)d_in[1];   // [512,1536]
  const float* Wproj = (const float*)d_in[2];  // [512,512]
  const float* bproj = (const float*)d_in[3];  // [512]
  float* out = (float*)d_out;                  // [4,2048,512]

  const int M = 8192;   // B*N
  const int C = 512;
  const int N3 = 1536;

  size_t off = 0;
  auto alloc = [&](size_t bytes) {
    void* p = (char*)d_ws + off;
    off += (bytes + 255) & ~(size_t)255;
    return p;
  };
  __hip_bfloat16* xb = (__hip_bfloat16*)alloc((size_t)M * C * 2);        // 8 MB
  __hip_bfloat16* wqkvT = (__hip_bfloat16*)alloc((size_t)N3 * C * 2);    // 1.5 MB
  __hip_bfloat16* wprojT = (__hip_bfloat16*)alloc((size_t)C * C * 2);    // 0.5 MB
  __hip_bfloat16* qkvb = (__hip_bfloat16*)alloc((size_t)M * N3 * 2);     // 25 MB
  __hip_bfloat16* attb = (__hip_bfloat16*)alloc((size_t)M * C * 2);      // 8 MB
  (void)ws_size;

  // casts
  {
    int n4 = M * C / 4;
    cast_bf16_kernel<<<(n4 + 255) / 256, 256, 0, stream>>>(x, xb, n4);
  }
  {
    int tot = C * N3;
    transpose_cast_kernel<<<(tot + 255) / 256, 256, 0, stream>>>(Wqkv, wqkvT, C, N3);
  }
  {
    int tot = C * C;
    transpose_cast_kernel<<<(tot + 255) / 256, 256, 0, stream>>>(Wproj, wprojT, C, C);
  }

  // GEMM1: qkv = x @ Wqkv   (M=8192, N=1536, K=512) -> bf16
  gemm_bt<1, 0><<<dim3(N3 / BN, M / BM), 256, 0, stream>>>(xb, wqkvT, qkvb, nullptr, M, N3, C);

  // banded attention
  local_attn_kernel<<<(4 * 8 * 2048) / 4, 256, 0, stream>>>(qkvb, attb);

  // GEMM2: out = att @ Wproj + bproj  (M=8192, N=512, K=512) -> fp32
  gemm_bt<0, 1><<<dim3(C / BN, M / BM), 256, 0, stream>>>(attb, wprojT, out, bproj, M, C, C);
}

// Round 2
// 81.461 us; speedup vs baseline: 2.2326x; 2.2326x over previous
//
#include <hip/hip_runtime.h>
#include <hip/hip_bf16.h>

typedef __attribute__((ext_vector_type(8))) short bf16x8;
typedef __attribute__((ext_vector_type(4))) float f32x4;

#define BM 128
#define BN 128
#define BK 32

// ---------------- cast kernels ----------------

__global__ __launch_bounds__(256) void cast_bf16_kernel(
    const float* __restrict__ in, __hip_bfloat16* __restrict__ out, int n4) {
  int i = blockIdx.x * 256 + threadIdx.x;
  if (i >= n4) return;
  const float4 v = reinterpret_cast<const float4*>(in)[i];
  __hip_bfloat16* o = out + (size_t)i * 4;
  o[0] = __float2bfloat16(v.x);
  o[1] = __float2bfloat16(v.y);
  o[2] = __float2bfloat16(v.z);
  o[3] = __float2bfloat16(v.w);
}

// in[R][C] (fp32) -> out[C][R] (bf16)   (write-coalesced)
__global__ __launch_bounds__(256) void transpose_cast_kernel(
    const float* __restrict__ in, __hip_bfloat16* __restrict__ out, int R, int C) {
  int idx = blockIdx.x * 256 + threadIdx.x;
  if (idx >= R * C) return;
  int r = idx % R;
  int c = idx / R;
  out[(size_t)c * R + r] = __float2bfloat16(in[(size_t)r * C + c]);
}

// ---------------- bf16 MFMA GEMM:  C[M,N] = A[M,K] @ BT[N,K]^T (+bias) ----------------
// batched via blockIdx.z with element strides sA/sB/sC

template <int OUT_BF16, int HAS_BIAS>
__global__ __launch_bounds__(256) void gemm_bt(
    const __hip_bfloat16* __restrict__ A,   // [M][K] row-major bf16
    const __hip_bfloat16* __restrict__ BT,  // [N][K] row-major bf16 (i.e. B transposed)
    void* __restrict__ Cout,                // [M][N] bf16 or fp32
    const float* __restrict__ bias,         // [N] fp32 (if HAS_BIAS)
    int M, int N, int K, size_t sA, size_t sB, size_t sC) {
  __shared__ __hip_bfloat16 As[BM * BK];  // 8 KB, linear row-major [128][32]
  __shared__ __hip_bfloat16 Bs[BN * BK];  // 8 KB, linear row-major [128][32]

  const int tid = threadIdx.x;
  const int lane = tid & 63;
  const int wid = tid >> 6;
  const int row0 = blockIdx.y * BM;
  const int col0 = blockIdx.x * BN;
  const int z = blockIdx.z;
  const __hip_bfloat16* Az = A + (size_t)z * sA;
  const __hip_bfloat16* Bz = BT + (size_t)z * sB;
  const int wrow = (wid >> 1) * 64;  // wave's 64x64 sub-tile
  const int wcol = (wid & 1) * 64;
  const int r15 = lane & 15;
  const int kb = lane >> 4;  // 0..3 -> k-group of 8

  f32x4 acc[4][4] = {};

  for (int k0 = 0; k0 < K; k0 += BK) {
#pragma unroll
    for (int i = 0; i < 2; ++i) {
      int c = wid * 128 + i * 64 + lane;
      int trow = c >> 2;
      int tcol = (c & 3) * 8;
      const __hip_bfloat16* ga = Az + (size_t)(row0 + trow) * K + k0 + tcol;
      const __hip_bfloat16* gb = Bz + (size_t)(col0 + trow) * K + k0 + tcol;
      __builtin_amdgcn_global_load_lds(
          (const __attribute__((address_space(1))) void*)ga,
          (__attribute__((address_space(3))) void*)(As + (size_t)(wid * 128 + i * 64) * 8),
          16, 0, 0);
      __builtin_amdgcn_global_load_lds(
          (const __attribute__((address_space(1))) void*)gb,
          (__attribute__((address_space(3))) void*)(Bs + (size_t)(wid * 128 + i * 64) * 8),
          16, 0, 0);
    }
    __syncthreads();

    const bf16x8* Av = reinterpret_cast<const bf16x8*>(As);
    const bf16x8* Bv = reinterpret_cast<const bf16x8*>(Bs);
    bf16x8 af[4], bfr[4];
#pragma unroll
    for (int m = 0; m < 4; ++m) af[m] = Av[(wrow + m * 16 + r15) * 4 + kb];
#pragma unroll
    for (int n = 0; n < 4; ++n) bfr[n] = Bv[(wcol + n * 16 + r15) * 4 + kb];
#pragma unroll
    for (int m = 0; m < 4; ++m)
#pragma unroll
      for (int n = 0; n < 4; ++n)
        acc[m][n] = __builtin_amdgcn_mfma_f32_16x16x32_bf16(af[m], bfr[n], acc[m][n], 0, 0, 0);
    __syncthreads();
  }

  const int orow_base = row0 + wrow + (lane >> 4) * 4;
#pragma unroll
  for (int m = 0; m < 4; ++m) {
#pragma unroll
    for (int r = 0; r < 4; ++r) {
      int row = orow_base + m * 16 + r;
#pragma unroll
      for (int n = 0; n < 4; ++n) {
        int col = col0 + wcol + n * 16 + r15;
        float v = acc[m][n][r];
        if (HAS_BIAS) v += bias[col];
        if (OUT_BF16)
          ((__hip_bfloat16*)Cout)[(size_t)z * sC + (size_t)row * N + col] = __float2bfloat16(v);
        else
          ((float*)Cout)[(size_t)z * sC + (size_t)row * N + col] = v;
      }
    }
  }
}

// ---------------- MFMA banded local attention ----------------
// qk: [B*N][1024] bf16 (q at +0, k at +512; per-head offset h*64)
// vt: [B][512][2048] bf16 (V transposed per batch: vt[b][h*64+d][n])
// att: [B*N][512] bf16
// one wave per (b, h, 16-row i-tile)
__global__ __launch_bounds__(256) void attn_mfma_kernel(
    const __hip_bfloat16* __restrict__ qk, const __hip_bfloat16* __restrict__ vt,
    __hip_bfloat16* __restrict__ att) {
  const int N = 2048;
  int unit = blockIdx.x * 4 + (threadIdx.x >> 6);
  int lane = threadIdx.x & 63;
  int b = unit >> 10;          // 8 heads * 128 tiles
  int h = (unit >> 7) & 7;
  int tile = unit & 127;
  int i0 = tile * 16;
  int jbase = i0 - 8;
  if (jbase < 0) jbase = 0;
  if (jbase > N - 32) jbase = N - 32;

  const int c = lane & 15;   // i_local for S^T; also d_local / output col
  const int g = lane >> 4;   // k-group

  // Q fragments (B operand): Q[i0+c][h*64 + kc*32 + g*8 + e]
  size_t qrow = (size_t)(b * N + i0 + c) * 1024 + h * 64;
  bf16x8 qf[2];
  qf[0] = *reinterpret_cast<const bf16x8*>(qk + qrow + g * 8);
  qf[1] = *reinterpret_cast<const bf16x8*>(qk + qrow + 32 + g * 8);

  // K fragments (A operand): K[jbase + jblk*16 + c][...]
  bf16x8 kf[2][2];
#pragma unroll
  for (int jblk = 0; jblk < 2; ++jblk) {
    size_t krow = (size_t)(b * N + jbase + jblk * 16 + c) * 1024 + 512 + h * 64;
    kf[jblk][0] = *reinterpret_cast<const bf16x8*>(qk + krow + g * 8);
    kf[jblk][1] = *reinterpret_cast<const bf16x8*>(qk + krow + 32 + g * 8);
  }

  // S^T[j][i]: lane holds i = i0 + c, j = jbase + jblk*16 + g*4 + r
  f32x4 sT[2] = {};
#pragma unroll
  for (int jblk = 0; jblk < 2; ++jblk)
#pragma unroll
    for (int kc = 0; kc < 2; ++kc)
      sT[jblk] = __builtin_amdgcn_mfma_f32_16x16x32_bf16(kf[jblk][kc], qf[kc], sT[jblk], 0, 0, 0);

  // scale + banded mask
  float s[2][4];
  const int i = i0 + c;
#pragma unroll
  for (int blk = 0; blk < 2; ++blk)
#pragma unroll
    for (int r = 0; r < 4; ++r) {
      int j = jbase + blk * 16 + g * 4 + r;
      int d = i - j;
      s[blk][r] = (d <= 8 && d >= -8) ? sT[blk][r] * 0.125f : -1e30f;
    }

  // softmax over j (per i = c): local 8 + cross-group (lanes c, 16+c, 32+c, 48+c)
  float m = -1e30f;
#pragma unroll
  for (int blk = 0; blk < 2; ++blk)
#pragma unroll
    for (int r = 0; r < 4; ++r) m = fmaxf(m, s[blk][r]);
  m = fmaxf(m, __shfl_xor(m, 16));
  m = fmaxf(m, __shfl_xor(m, 32));

  float p[2][4];
  float den = 0.f;
#pragma unroll
  for (int blk = 0; blk < 2; ++blk)
#pragma unroll
    for (int r = 0; r < 4; ++r) {
      p[blk][r] = __expf(s[blk][r] - m);
      den += p[blk][r];
    }
  den += __shfl_xor(den, 16);
  den += __shfl_xor(den, 32);
  float inv = 1.0f / den;
#pragma unroll
  for (int blk = 0; blk < 2; ++blk)
#pragma unroll
    for (int r = 0; r < 4; ++r) p[blk][r] *= inv;

  // pack P to bf16 pairs and redistribute to A-fragment layout:
  // target lane (g,c) needs j = jbase + 8g + e  (e = 0..7)
  auto pack2 = [](float a, float bb) -> unsigned int {
    __hip_bfloat16 lo = __float2bfloat16(a), hi = __float2bfloat16(bb);
    unsigned short ls = *reinterpret_cast<unsigned short*>(&lo);
    unsigned short hs = *reinterpret_cast<unsigned short*>(&hi);
    return (unsigned int)ls | ((unsigned int)hs << 16);
  };
  unsigned int w00 = pack2(p[0][0], p[0][1]);
  unsigned int w01 = pack2(p[0][2], p[0][3]);
  unsigned int w10 = pack2(p[1][0], p[1][1]);
  unsigned int w11 = pack2(p[1][2], p[1][3]);

  int L1 = ((g & 1) << 5) | c;  // source group 2*(g&1)
  int L2 = L1 + 16;             // source group 2*(g&1)+1
  unsigned int a0 = (unsigned int)__shfl((int)w00, L1);
  unsigned int b0 = (unsigned int)__shfl((int)w10, L1);
  unsigned int a1 = (unsigned int)__shfl((int)w01, L1);
  unsigned int b1 = (unsigned int)__shfl((int)w11, L1);
  unsigned int a2 = (unsigned int)__shfl((int)w00, L2);
  unsigned int b2 = (unsigned int)__shfl((int)w10, L2);
  unsigned int a3 = (unsigned int)__shfl((int)w01, L2);
  unsigned int b3 = (unsigned int)__shfl((int)w11, L2);
  bool hiblk = (g >> 1) != 0;
  union {
    unsigned int u[4];
    bf16x8 v;
  } pf;
  pf.u[0] = hiblk ? b0 : a0;
  pf.u[1] = hiblk ? b1 : a1;
  pf.u[2] = hiblk ? b2 : a2;
  pf.u[3] = hiblk ? b3 : a3;

  // PV: O[i][d] = sum_j P[i][j] V[j][d]; V^T fragment: 8 consecutive n at fixed d
  const __hip_bfloat16* vtb = vt + ((size_t)(b * 8 + h) * 64) * 2048;
  f32x4 o[4];
#pragma unroll
  for (int dblk = 0; dblk < 4; ++dblk) {
    bf16x8 vf = *reinterpret_cast<const bf16x8*>(vtb + (size_t)(dblk * 16 + c) * 2048 + jbase + g * 8);
    f32x4 z = {};
    o[dblk] = __builtin_amdgcn_mfma_f32_16x16x32_bf16(pf.v, vf, z, 0, 0, 0);
  }

  // write: row i = i0 + 4g + r, col = h*64 + dblk*16 + c
#pragma unroll
  for (int dblk = 0; dblk < 4; ++dblk)
#pragma unroll
    for (int r = 0; r < 4; ++r)
      att[(size_t)(b * N + i0 + 4 * g + r) * 512 + h * 64 + dblk * 16 + c] =
          __float2bfloat16(o[dblk][r]);
}

// ---------------- launch ----------------

extern "C" void kernel_launch(void* const* d_in, const int* in_sizes, int n_in,
                              void* d_out, int out_size, void* d_ws, size_t ws_size,
                              hipStream_t stream) {
  const float* x = (const float*)d_in[0];      // [4,2048,512]
  const float* Wqkv = (const float*)d_in[1];   // [512,1536]
  const float* Wproj = (const float*)d_in[2];  // [512,512]
  const float* bproj = (const float*)d_in[3];  // [512]
  float* out = (float*)d_out;                  // [4,2048,512]

  const int M = 8192;  // B*N
  const int C = 512;
  const int N3 = 1536;

  size_t off = 0;
  auto alloc = [&](size_t bytes) {
    void* p = (char*)d_ws + off;
    off += (bytes + 255) & ~(size_t)255;
    return p;
  };
  __hip_bfloat16* xb = (__hip_bfloat16*)alloc((size_t)M * C * 2);      // 8 MB
  __hip_bfloat16* wqkvT = (__hip_bfloat16*)alloc((size_t)N3 * C * 2);  // 1.5 MB
  __hip_bfloat16* wprojT = (__hip_bfloat16*)alloc((size_t)C * C * 2);  // 0.5 MB
  __hip_bfloat16* qkb = (__hip_bfloat16*)alloc((size_t)M * 1024 * 2);  // 16 MB (q,k)
  __hip_bfloat16* vtb = (__hip_bfloat16*)alloc((size_t)4 * 512 * 2048 * 2);  // 8 MB
  __hip_bfloat16* attb = (__hip_bfloat16*)alloc((size_t)M * C * 2);    // 8 MB
  (void)ws_size;

  // casts
  {
    int n4 = M * C / 4;
    cast_bf16_kernel<<<(n4 + 255) / 256, 256, 0, stream>>>(x, xb, n4);
  }
  {
    int tot = C * N3;
    transpose_cast_kernel<<<(tot + 255) / 256, 256, 0, stream>>>(Wqkv, wqkvT, C, N3);
  }
  {
    int tot = C * C;
    transpose_cast_kernel<<<(tot + 255) / 256, 256, 0, stream>>>(Wproj, wprojT, C, C);
  }

  // GEMM1: [q|k] = x @ Wqkv[:, :1024]   (M=8192, N=1024, K=512) -> bf16
  gemm_bt<1, 0><<<dim3(1024 / BN, M / BM, 1), 256, 0, stream>>>(
      xb, wqkvT, qkb, nullptr, M, 1024, C, 0, 0, 0);

  // GEMM-V: per batch b, V_b^T = Wv^T @ x_b^T  (M=512, N=2048, K=512) -> bf16
  gemm_bt<1, 0><<<dim3(2048 / BN, 512 / BM, 4), 256, 0, stream>>>(
      wqkvT + (size_t)1024 * 512, xb, vtb, nullptr, 512, 2048, C,
      0, (size_t)2048 * 512, (size_t)512 * 2048);

  // banded attention (MFMA): 4096 waves, 4 per block
  attn_mfma_kernel<<<1024, 256, 0, stream>>>(qkb, vtb, attb);

  // GEMM2: out = att @ Wproj + bproj  (M=8192, N=512, K=512) -> fp32
  gemm_bt<0, 1><<<dim3(C / BN, M / BM, 1), 256, 0, stream>>>(
      attb, wprojT, out, bproj, M, C, C, 0, 0, 0);
}

// Round 3
// 60.976 us; speedup vs baseline: 2.9826x; 1.3359x over previous
//
#include <hip/hip_runtime.h>
#include <hip/hip_bf16.h>

typedef __attribute__((ext_vector_type(8))) short bf16x8;
typedef __attribute__((ext_vector_type(4))) float f32x4;

#define BM 128
#define BN 128
#define BK 64

// ---------------- fused prep: x cast + Wqkv^T cast + Wproj^T cast ----------------

__global__ __launch_bounds__(256) void prep_kernel(
    const float* __restrict__ x, const float* __restrict__ Wqkv,
    const float* __restrict__ Wproj, __hip_bfloat16* __restrict__ xb,
    __hip_bfloat16* __restrict__ wqkvT, __hip_bfloat16* __restrict__ wprojT) {
  int bid = blockIdx.x;
  int tid = threadIdx.x;
  if (bid < 4096) {
    // cast x: 8192*512 fp32 -> bf16, 4 per thread
    int i = bid * 256 + tid;  // < 1048576
    const float4 v = reinterpret_cast<const float4*>(x)[i];
    __hip_bfloat16* o = xb + (size_t)i * 4;
    o[0] = __float2bfloat16(v.x);
    o[1] = __float2bfloat16(v.y);
    o[2] = __float2bfloat16(v.z);
    o[3] = __float2bfloat16(v.w);
  } else if (bid < 4096 + 3072) {
    // Wqkv [512][1536] -> wqkvT [1536][512] bf16
    int idx = (bid - 4096) * 256 + tid;  // < 786432
    int r = idx & 511;
    int cc = idx >> 9;
    wqkvT[(size_t)cc * 512 + r] = __float2bfloat16(Wqkv[(size_t)r * 1536 + cc]);
  } else {
    // Wproj [512][512] -> wprojT [512][512] bf16
    int idx = (bid - 4096 - 3072) * 256 + tid;  // < 262144
    int r = idx & 511;
    int cc = idx >> 9;
    wprojT[(size_t)cc * 512 + r] = __float2bfloat16(Wproj[(size_t)r * 512 + cc]);
  }
}

// ---------------- bf16 MFMA GEMM:  C[M,N] = A[M,K] @ BT[N,K]^T (+bias) ----------------
// BK=64, XOR-swizzled LDS (k-chunk ^= row&7; inverse-swizzled global source,
// linear global_load_lds dest, swizzled ds_read — rule "both sides or neither").

template <int OUT_BF16, int HAS_BIAS>
__global__ __launch_bounds__(256) void gemm_bt(
    const __hip_bfloat16* __restrict__ A,   // [M][K] row-major bf16
    const __hip_bfloat16* __restrict__ BT,  // [N][K] row-major bf16
    void* __restrict__ Cout,                // [M][N] bf16 or fp32
    const float* __restrict__ bias,         // [N] fp32 (if HAS_BIAS)
    int M, int N, int K) {
  __shared__ __hip_bfloat16 As[BM * BK];  // 16 KB
  __shared__ __hip_bfloat16 Bs[BN * BK];  // 16 KB

  const int tid = threadIdx.x;
  const int lane = tid & 63;
  const int wid = tid >> 6;
  const int row0 = blockIdx.y * BM;
  const int col0 = blockIdx.x * BN;
  const int wrow = (wid >> 1) * 64;
  const int wcol = (wid & 1) * 64;
  const int r15 = lane & 15;
  const int g = lane >> 4;  // 0..3

  f32x4 acc[4][4] = {};

  for (int k0 = 0; k0 < K; k0 += BK) {
#pragma unroll
    for (int i = 0; i < 4; ++i) {
      // chunk id c in [0,1024): 8 bf16 (16B) per chunk; row = c>>3, logical kchunk = c&7
      int c = wid * 256 + i * 64 + lane;
      int trow = c >> 3;
      int tcol = ((c & 7) ^ (trow & 7)) * 8;  // inverse-swizzled source
      const __hip_bfloat16* ga = A + (size_t)(row0 + trow) * K + k0 + tcol;
      const __hip_bfloat16* gb = BT + (size_t)(col0 + trow) * K + k0 + tcol;
      __builtin_amdgcn_global_load_lds(
          (const __attribute__((address_space(1))) void*)ga,
          (__attribute__((address_space(3))) void*)(As + (size_t)(wid * 256 + i * 64) * 8),
          16, 0, 0);
      __builtin_amdgcn_global_load_lds(
          (const __attribute__((address_space(1))) void*)gb,
          (__attribute__((address_space(3))) void*)(Bs + (size_t)(wid * 256 + i * 64) * 8),
          16, 0, 0);
    }
    __syncthreads();

    const bf16x8* Av = reinterpret_cast<const bf16x8*>(As);
    const bf16x8* Bv = reinterpret_cast<const bf16x8*>(Bs);
#pragma unroll
    for (int kc = 0; kc < 2; ++kc) {
      bf16x8 af[4], bfr[4];
#pragma unroll
      for (int m = 0; m < 4; ++m) {
        int ra = wrow + m * 16 + r15;
        af[m] = Av[ra * 8 + ((kc * 4 + g) ^ (ra & 7))];
      }
#pragma unroll
      for (int n = 0; n < 4; ++n) {
        int rb = wcol + n * 16 + r15;
        bfr[n] = Bv[rb * 8 + ((kc * 4 + g) ^ (rb & 7))];
      }
#pragma unroll
      for (int m = 0; m < 4; ++m)
#pragma unroll
        for (int n = 0; n < 4; ++n)
          acc[m][n] = __builtin_amdgcn_mfma_f32_16x16x32_bf16(af[m], bfr[n], acc[m][n], 0, 0, 0);
    }
    __syncthreads();
  }

  // epilogue: D row = g*4 + reg, col = r15 within each 16x16 tile
  const int orow_base = row0 + wrow + g * 4;
#pragma unroll
  for (int m = 0; m < 4; ++m) {
#pragma unroll
    for (int r = 0; r < 4; ++r) {
      int row = orow_base + m * 16 + r;
#pragma unroll
      for (int n = 0; n < 4; ++n) {
        int col = col0 + wcol + n * 16 + r15;
        float v = acc[m][n][r];
        if (HAS_BIAS) v += bias[col];
        if (OUT_BF16)
          ((__hip_bfloat16*)Cout)[(size_t)row * N + col] = __float2bfloat16(v);
        else
          ((float*)Cout)[(size_t)row * N + col] = v;
      }
    }
  }
}

// ---------------- MFMA banded local attention ----------------
// qkv: [B*N][1536] bf16 (q at +0, k at +512, v at +1024; per-head offset h*64)
// att: [B*N][512] bf16
// one wave per (b, h, 16-row i-tile)
__global__ __launch_bounds__(256) void attn_mfma_kernel(
    const __hip_bfloat16* __restrict__ qkv, __hip_bfloat16* __restrict__ att) {
  const int N = 2048;
  int unit = blockIdx.x * 4 + (threadIdx.x >> 6);
  int lane = threadIdx.x & 63;
  int b = unit >> 10;          // 8 heads * 128 tiles
  int h = (unit >> 7) & 7;
  int tile = unit & 127;
  int i0 = tile * 16;
  int jbase = i0 - 8;
  if (jbase < 0) jbase = 0;
  if (jbase > N - 32) jbase = N - 32;

  const int c = lane & 15;   // i_local for S^T; also d_local / output col
  const int g = lane >> 4;   // k-group

  // Q fragments (B operand): Q[i0+c][h*64 + kc*32 + g*8 + e]
  size_t qrow = (size_t)(b * N + i0 + c) * 1536 + h * 64;
  bf16x8 qf[2];
  qf[0] = *reinterpret_cast<const bf16x8*>(qkv + qrow + g * 8);
  qf[1] = *reinterpret_cast<const bf16x8*>(qkv + qrow + 32 + g * 8);

  // K fragments (A operand): K[jbase + jblk*16 + c][...]
  bf16x8 kf[2][2];
#pragma unroll
  for (int jblk = 0; jblk < 2; ++jblk) {
    size_t krow = (size_t)(b * N + jbase + jblk * 16 + c) * 1536 + 512 + h * 64;
    kf[jblk][0] = *reinterpret_cast<const bf16x8*>(qkv + krow + g * 8);
    kf[jblk][1] = *reinterpret_cast<const bf16x8*>(qkv + krow + 32 + g * 8);
  }

  // V fragments (B operand for PV): lane (c,g) elem e needs V[jbase+8g+e][d0+c].
  // Row-major qkv → 8 scalar u16 loads per dblk, issued early to hide latency.
  const __hip_bfloat16* vrow[8];
#pragma unroll
  for (int e = 0; e < 8; ++e)
    vrow[e] = qkv + (size_t)(b * N + jbase + 8 * g + e) * 1536 + 1024 + h * 64 + c;
  union VU { unsigned short us[8]; bf16x8 v; };
  VU vf[4];
#pragma unroll
  for (int dblk = 0; dblk < 4; ++dblk)
#pragma unroll
    for (int e = 0; e < 8; ++e)
      vf[dblk].us[e] = *reinterpret_cast<const unsigned short*>(vrow[e] + dblk * 16);

  // S^T[j][i]: lane holds i = i0 + c, j = jbase + jblk*16 + g*4 + r
  f32x4 sT[2] = {};
#pragma unroll
  for (int jblk = 0; jblk < 2; ++jblk)
#pragma unroll
    for (int kc = 0; kc < 2; ++kc)
      sT[jblk] = __builtin_amdgcn_mfma_f32_16x16x32_bf16(kf[jblk][kc], qf[kc], sT[jblk], 0, 0, 0);

  // scale + banded mask
  float s[2][4];
  const int i = i0 + c;
#pragma unroll
  for (int blk = 0; blk < 2; ++blk)
#pragma unroll
    for (int r = 0; r < 4; ++r) {
      int j = jbase + blk * 16 + g * 4 + r;
      int d = i - j;
      s[blk][r] = (d <= 8 && d >= -8) ? sT[blk][r] * 0.125f : -1e30f;
    }

  // softmax over j (per i = c): local 8 + cross-group reduce
  float m = -1e30f;
#pragma unroll
  for (int blk = 0; blk < 2; ++blk)
#pragma unroll
    for (int r = 0; r < 4; ++r) m = fmaxf(m, s[blk][r]);
  m = fmaxf(m, __shfl_xor(m, 16));
  m = fmaxf(m, __shfl_xor(m, 32));

  float p[2][4];
  float den = 0.f;
#pragma unroll
  for (int blk = 0; blk < 2; ++blk)
#pragma unroll
    for (int r = 0; r < 4; ++r) {
      p[blk][r] = __expf(s[blk][r] - m);
      den += p[blk][r];
    }
  den += __shfl_xor(den, 16);
  den += __shfl_xor(den, 32);
  float inv = 1.0f / den;
#pragma unroll
  for (int blk = 0; blk < 2; ++blk)
#pragma unroll
    for (int r = 0; r < 4; ++r) p[blk][r] *= inv;

  // pack P to bf16 pairs and redistribute to A-fragment layout:
  // target lane (c,g) needs j = jbase + 8g + e  (e = 0..7)
  auto pack2 = [](float a, float bb) -> unsigned int {
    __hip_bfloat16 lo = __float2bfloat16(a), hi = __float2bfloat16(bb);
    unsigned short ls = *reinterpret_cast<unsigned short*>(&lo);
    unsigned short hs = *reinterpret_cast<unsigned short*>(&hi);
    return (unsigned int)ls | ((unsigned int)hs << 16);
  };
  unsigned int w00 = pack2(p[0][0], p[0][1]);
  unsigned int w01 = pack2(p[0][2], p[0][3]);
  unsigned int w10 = pack2(p[1][0], p[1][1]);
  unsigned int w11 = pack2(p[1][2], p[1][3]);

  int L1 = ((g & 1) << 5) | c;  // source group 2*(g&1)
  int L2 = L1 + 16;             // source group 2*(g&1)+1
  unsigned int a0 = (unsigned int)__shfl((int)w00, L1);
  unsigned int b0 = (unsigned int)__shfl((int)w10, L1);
  unsigned int a1 = (unsigned int)__shfl((int)w01, L1);
  unsigned int b1 = (unsigned int)__shfl((int)w11, L1);
  unsigned int a2 = (unsigned int)__shfl((int)w00, L2);
  unsigned int b2 = (unsigned int)__shfl((int)w10, L2);
  unsigned int a3 = (unsigned int)__shfl((int)w01, L2);
  unsigned int b3 = (unsigned int)__shfl((int)w11, L2);
  bool hiblk = (g >> 1) != 0;
  union {
    unsigned int u[4];
    bf16x8 v;
  } pf;
  pf.u[0] = hiblk ? b0 : a0;
  pf.u[1] = hiblk ? b1 : a1;
  pf.u[2] = hiblk ? b2 : a2;
  pf.u[3] = hiblk ? b3 : a3;

  // PV: O[i][d] = sum_j P[i][j] V[j][d]
  f32x4 o[4];
#pragma unroll
  for (int dblk = 0; dblk < 4; ++dblk) {
    f32x4 z = {};
    o[dblk] = __builtin_amdgcn_mfma_f32_16x16x32_bf16(pf.v, vf[dblk].v, z, 0, 0, 0);
  }

  // write: row i = i0 + 4g + r, col = h*64 + dblk*16 + c
#pragma unroll
  for (int dblk = 0; dblk < 4; ++dblk)
#pragma unroll
    for (int r = 0; r < 4; ++r)
      att[(size_t)(b * N + i0 + 4 * g + r) * 512 + h * 64 + dblk * 16 + c] =
          __float2bfloat16(o[dblk][r]);
}

// ---------------- launch ----------------

extern "C" void kernel_launch(void* const* d_in, const int* in_sizes, int n_in,
                              void* d_out, int out_size, void* d_ws, size_t ws_size,
                              hipStream_t stream) {
  const float* x = (const float*)d_in[0];      // [4,2048,512]
  const float* Wqkv = (const float*)d_in[1];   // [512,1536]
  const float* Wproj = (const float*)d_in[2];  // [512,512]
  const float* bproj = (const float*)d_in[3];  // [512]
  float* out = (float*)d_out;                  // [4,2048,512]
  (void)in_sizes; (void)n_in; (void)out_size; (void)ws_size;

  const int M = 8192;  // B*N
  const int C = 512;
  const int N3 = 1536;

  size_t off = 0;
  auto alloc = [&](size_t bytes) {
    void* p = (char*)d_ws + off;
    off += (bytes + 255) & ~(size_t)255;
    return p;
  };
  __hip_bfloat16* xb = (__hip_bfloat16*)alloc((size_t)M * C * 2);       // 8 MB
  __hip_bfloat16* wqkvT = (__hip_bfloat16*)alloc((size_t)N3 * C * 2);   // 1.5 MB
  __hip_bfloat16* wprojT = (__hip_bfloat16*)alloc((size_t)C * C * 2);   // 0.5 MB
  __hip_bfloat16* qkvb = (__hip_bfloat16*)alloc((size_t)M * N3 * 2);    // 25 MB
  __hip_bfloat16* attb = (__hip_bfloat16*)alloc((size_t)M * C * 2);     // 8 MB

  // fused prep: x cast (4096 blocks) + WqkvT (3072) + WprojT (1024)
  prep_kernel<<<8192, 256, 0, stream>>>(x, Wqkv, Wproj, xb, wqkvT, wprojT);

  // GEMM1: qkv = x @ Wqkv   (M=8192, N=1536, K=512) -> bf16
  gemm_bt<1, 0><<<dim3(N3 / BN, M / BM), 256, 0, stream>>>(
      xb, wqkvT, qkvb, nullptr, M, N3, C);

  // banded attention (MFMA): 4096 waves, 4 per block
  attn_mfma_kernel<<<1024, 256, 0, stream>>>(qkvb, attb);

  // GEMM2: out = att @ Wproj + bproj  (M=8192, N=512, K=512) -> fp32
  gemm_bt<0, 1><<<dim3(C / BN, M / BM), 256, 0, stream>>>(
      attb, wprojT, out, bproj, M, C, C);
}

// Round 4
// 56.218 us; speedup vs baseline: 3.2351x; 1.0846x over previous
//
#include <hip/hip_runtime.h>
#include <hip/hip_bf16.h>

typedef __attribute__((ext_vector_type(8))) short bf16x8;
typedef __attribute__((ext_vector_type(4))) float f32x4;

#define BM 128
#define BN 128
#define BK 64

// ---------------- fused prep: x cast + LDS-tiled weight transposes ----------------
// grid: [0,4096) x-cast | [4096,4288) WqkvT (8x24 tiles) | [4288,4352) WprojT (8x8)

__global__ __launch_bounds__(256) void prep_kernel(
    const float* __restrict__ x, const float* __restrict__ Wqkv,
    const float* __restrict__ Wproj, __hip_bfloat16* __restrict__ xb,
    __hip_bfloat16* __restrict__ wqkvT, __hip_bfloat16* __restrict__ wprojT) {
  int bid = blockIdx.x;
  int tid = threadIdx.x;
  if (bid < 4096) {
    int i = bid * 256 + tid;  // < 1048576
    const float4 v = reinterpret_cast<const float4*>(x)[i];
    __hip_bfloat16* o = xb + (size_t)i * 4;
    o[0] = __float2bfloat16(v.x);
    o[1] = __float2bfloat16(v.y);
    o[2] = __float2bfloat16(v.z);
    o[3] = __float2bfloat16(v.w);
    return;
  }
  __shared__ float t[64][65];
  const float* src;
  __hip_bfloat16* dst;
  int C;  // source col count
  int rb, cb;
  if (bid < 4288) {
    int b = bid - 4096;  // 8 row-tiles x 24 col-tiles
    rb = b & 7; cb = b >> 3;
    src = Wqkv; dst = wqkvT; C = 1536;
  } else {
    int b = bid - 4288;  // 8 x 8
    rb = b & 7; cb = b >> 3;
    src = Wproj; dst = wprojT; C = 512;
  }
  int r0 = rb * 64, c0 = cb * 64;
  int ty = tid >> 6, tx = tid & 63;
#pragma unroll
  for (int i = 0; i < 16; ++i) {
    int r = ty * 16 + i;
    t[r][tx] = src[(size_t)(r0 + r) * C + c0 + tx];
  }
  __syncthreads();
#pragma unroll
  for (int i = 0; i < 16; ++i) {
    int cr = ty * 16 + i;
    dst[(size_t)(c0 + cr) * 512 + r0 + tx] = __float2bfloat16(t[tx][cr]);
  }
}

// ---------------- bf16 MFMA GEMM:  C[M,N] = A[M,K] @ BT[N,K]^T (+bias) ----------------
// 2-phase double-buffered: STAGE(t+1) issued before compute(t); one barrier/iter.
// XOR-swizzled LDS (k-chunk ^= row&7), inverse-swizzled global source (rule: both sides).
// XCD-bijective block swizzle (grid % 8 == 0 for all our shapes).

template <int OUT_BF16, int HAS_BIAS>
__global__ __launch_bounds__(256, 2) void gemm_bt(
    const __hip_bfloat16* __restrict__ A,   // [M][K] row-major bf16
    const __hip_bfloat16* __restrict__ BT,  // [N][K] row-major bf16
    void* __restrict__ Cout,                // [M][N] bf16 or fp32
    const float* __restrict__ bias,         // [N] fp32 (if HAS_BIAS)
    int M, int N, int K) {
  __shared__ __hip_bfloat16 As[2][BM * BK];  // 2 x 16 KB
  __shared__ __hip_bfloat16 Bs[2][BN * BK];  // 2 x 16 KB

  const int tid = threadIdx.x;
  const int lane = tid & 63;
  const int wid = tid >> 6;

  // XCD-aware bijective swizzle of the linear block id
  const int nwg = gridDim.x * gridDim.y;
  const int lin = blockIdx.y * gridDim.x + blockIdx.x;
  const int cpx = nwg >> 3;  // nwg % 8 == 0 guaranteed by launch
  const int swz = (lin & 7) * cpx + (lin >> 3);
  const int bx = swz % gridDim.x;
  const int by = swz / gridDim.x;

  const int row0 = by * BM;
  const int col0 = bx * BN;
  const int wrow = (wid >> 1) * 64;
  const int wcol = (wid & 1) * 64;
  const int r15 = lane & 15;
  const int g = lane >> 4;  // 0..3

  f32x4 acc[4][4] = {};

  auto stage = [&](int buf, int k0) {
#pragma unroll
    for (int i = 0; i < 4; ++i) {
      // chunk id c in [0,1024): 8 bf16 (16B); row = c>>3, logical kchunk = c&7
      int c = wid * 256 + i * 64 + lane;
      int trow = c >> 3;
      int tcol = ((c & 7) ^ (trow & 7)) * 8;  // inverse-swizzled source
      const __hip_bfloat16* ga = A + (size_t)(row0 + trow) * K + k0 + tcol;
      const __hip_bfloat16* gb = BT + (size_t)(col0 + trow) * K + k0 + tcol;
      __builtin_amdgcn_global_load_lds(
          (const __attribute__((address_space(1))) void*)ga,
          (__attribute__((address_space(3))) void*)(&As[buf][0] + (size_t)(wid * 256 + i * 64) * 8),
          16, 0, 0);
      __builtin_amdgcn_global_load_lds(
          (const __attribute__((address_space(1))) void*)gb,
          (__attribute__((address_space(3))) void*)(&Bs[buf][0] + (size_t)(wid * 256 + i * 64) * 8),
          16, 0, 0);
    }
  };

  const int NT = K / BK;
  stage(0, 0);
  __syncthreads();  // drains vmcnt(0): buf0 ready

  int cur = 0;
  for (int t = 0; t < NT; ++t) {
    if (t + 1 < NT) stage(cur ^ 1, (t + 1) * BK);  // loads fly during compute

    const bf16x8* Av = reinterpret_cast<const bf16x8*>(&As[cur][0]);
    const bf16x8* Bv = reinterpret_cast<const bf16x8*>(&Bs[cur][0]);
#pragma unroll
    for (int kc = 0; kc < 2; ++kc) {
      bf16x8 af[4], bfr[4];
#pragma unroll
      for (int m = 0; m < 4; ++m) {
        int ra = wrow + m * 16 + r15;
        af[m] = Av[ra * 8 + ((kc * 4 + g) ^ (ra & 7))];
      }
#pragma unroll
      for (int n = 0; n < 4; ++n) {
        int rb = wcol + n * 16 + r15;
        bfr[n] = Bv[rb * 8 + ((kc * 4 + g) ^ (rb & 7))];
      }
#pragma unroll
      for (int m = 0; m < 4; ++m)
#pragma unroll
        for (int n = 0; n < 4; ++n)
          acc[m][n] = __builtin_amdgcn_mfma_f32_16x16x32_bf16(af[m], bfr[n], acc[m][n], 0, 0, 0);
    }
    if (t + 1 < NT) {
      __syncthreads();  // vmcnt(0)+lgkmcnt(0)+barrier: next buf ready, reads done
      cur ^= 1;
    }
  }

  // epilogue: D row = g*4 + reg, col = r15 within each 16x16 tile
  const int orow_base = row0 + wrow + g * 4;
#pragma unroll
  for (int m = 0; m < 4; ++m) {
#pragma unroll
    for (int r = 0; r < 4; ++r) {
      int row = orow_base + m * 16 + r;
#pragma unroll
      for (int n = 0; n < 4; ++n) {
        int col = col0 + wcol + n * 16 + r15;
        float v = acc[m][n][r];
        if (HAS_BIAS) v += bias[col];
        if (OUT_BF16)
          ((__hip_bfloat16*)Cout)[(size_t)row * N + col] = __float2bfloat16(v);
        else
          ((float*)Cout)[(size_t)row * N + col] = v;
      }
    }
  }
}

// ---------------- MFMA banded local attention ----------------
// qkv: [B*N][1536] bf16 (q at +0, k at +512, v at +1024; per-head offset h*64)
// att: [B*N][512] bf16
// one wave per (b, h, 16-row i-tile)
__global__ __launch_bounds__(256) void attn_mfma_kernel(
    const __hip_bfloat16* __restrict__ qkv, __hip_bfloat16* __restrict__ att) {
  const int N = 2048;
  int unit = blockIdx.x * 4 + (threadIdx.x >> 6);
  int lane = threadIdx.x & 63;
  int b = unit >> 10;          // 8 heads * 128 tiles
  int h = (unit >> 7) & 7;
  int tile = unit & 127;
  int i0 = tile * 16;
  int jbase = i0 - 8;
  if (jbase < 0) jbase = 0;
  if (jbase > N - 32) jbase = N - 32;

  const int c = lane & 15;   // i_local for S^T; also d_local / output col
  const int g = lane >> 4;   // k-group

  // Q fragments (B operand): Q[i0+c][h*64 + kc*32 + g*8 + e]
  size_t qrow = (size_t)(b * N + i0 + c) * 1536 + h * 64;
  bf16x8 qf[2];
  qf[0] = *reinterpret_cast<const bf16x8*>(qkv + qrow + g * 8);
  qf[1] = *reinterpret_cast<const bf16x8*>(qkv + qrow + 32 + g * 8);

  // K fragments (A operand): K[jbase + jblk*16 + c][...]
  bf16x8 kf[2][2];
#pragma unroll
  for (int jblk = 0; jblk < 2; ++jblk) {
    size_t krow = (size_t)(b * N + jbase + jblk * 16 + c) * 1536 + 512 + h * 64;
    kf[jblk][0] = *reinterpret_cast<const bf16x8*>(qkv + krow + g * 8);
    kf[jblk][1] = *reinterpret_cast<const bf16x8*>(qkv + krow + 32 + g * 8);
  }

  // V fragments (B operand for PV): lane (c,g) elem e needs V[jbase+8g+e][d0+c].
  const __hip_bfloat16* vrow[8];
#pragma unroll
  for (int e = 0; e < 8; ++e)
    vrow[e] = qkv + (size_t)(b * N + jbase + 8 * g + e) * 1536 + 1024 + h * 64 + c;
  union VU { unsigned short us[8]; bf16x8 v; };
  VU vf[4];
#pragma unroll
  for (int dblk = 0; dblk < 4; ++dblk)
#pragma unroll
    for (int e = 0; e < 8; ++e)
      vf[dblk].us[e] = *reinterpret_cast<const unsigned short*>(vrow[e] + dblk * 16);

  // S^T[j][i]: lane holds i = i0 + c, j = jbase + jblk*16 + g*4 + r
  f32x4 sT[2] = {};
#pragma unroll
  for (int jblk = 0; jblk < 2; ++jblk)
#pragma unroll
    for (int kc = 0; kc < 2; ++kc)
      sT[jblk] = __builtin_amdgcn_mfma_f32_16x16x32_bf16(kf[jblk][kc], qf[kc], sT[jblk], 0, 0, 0);

  // scale + banded mask
  float s[2][4];
  const int i = i0 + c;
#pragma unroll
  for (int blk = 0; blk < 2; ++blk)
#pragma unroll
    for (int r = 0; r < 4; ++r) {
      int j = jbase + blk * 16 + g * 4 + r;
      int d = i - j;
      s[blk][r] = (d <= 8 && d >= -8) ? sT[blk][r] * 0.125f : -1e30f;
    }

  // softmax over j (per i = c)
  float m = -1e30f;
#pragma unroll
  for (int blk = 0; blk < 2; ++blk)
#pragma unroll
    for (int r = 0; r < 4; ++r) m = fmaxf(m, s[blk][r]);
  m = fmaxf(m, __shfl_xor(m, 16));
  m = fmaxf(m, __shfl_xor(m, 32));

  float p[2][4];
  float den = 0.f;
#pragma unroll
  for (int blk = 0; blk < 2; ++blk)
#pragma unroll
    for (int r = 0; r < 4; ++r) {
      p[blk][r] = __expf(s[blk][r] - m);
      den += p[blk][r];
    }
  den += __shfl_xor(den, 16);
  den += __shfl_xor(den, 32);
  float inv = 1.0f / den;
#pragma unroll
  for (int blk = 0; blk < 2; ++blk)
#pragma unroll
    for (int r = 0; r < 4; ++r) p[blk][r] *= inv;

  // pack P to bf16 pairs and redistribute to A-fragment layout
  auto pack2 = [](float a, float bb) -> unsigned int {
    __hip_bfloat16 lo = __float2bfloat16(a), hi = __float2bfloat16(bb);
    unsigned short ls = *reinterpret_cast<unsigned short*>(&lo);
    unsigned short hs = *reinterpret_cast<unsigned short*>(&hi);
    return (unsigned int)ls | ((unsigned int)hs << 16);
  };
  unsigned int w00 = pack2(p[0][0], p[0][1]);
  unsigned int w01 = pack2(p[0][2], p[0][3]);
  unsigned int w10 = pack2(p[1][0], p[1][1]);
  unsigned int w11 = pack2(p[1][2], p[1][3]);

  int L1 = ((g & 1) << 5) | c;
  int L2 = L1 + 16;
  unsigned int a0 = (unsigned int)__shfl((int)w00, L1);
  unsigned int b0 = (unsigned int)__shfl((int)w10, L1);
  unsigned int a1 = (unsigned int)__shfl((int)w01, L1);
  unsigned int b1 = (unsigned int)__shfl((int)w11, L1);
  unsigned int a2 = (unsigned int)__shfl((int)w00, L2);
  unsigned int b2 = (unsigned int)__shfl((int)w10, L2);
  unsigned int a3 = (unsigned int)__shfl((int)w01, L2);
  unsigned int b3 = (unsigned int)__shfl((int)w11, L2);
  bool hiblk = (g >> 1) != 0;
  union {
    unsigned int u[4];
    bf16x8 v;
  } pf;
  pf.u[0] = hiblk ? b0 : a0;
  pf.u[1] = hiblk ? b1 : a1;
  pf.u[2] = hiblk ? b2 : a2;
  pf.u[3] = hiblk ? b3 : a3;

  // PV
  f32x4 o[4];
#pragma unroll
  for (int dblk = 0; dblk < 4; ++dblk) {
    f32x4 z = {};
    o[dblk] = __builtin_amdgcn_mfma_f32_16x16x32_bf16(pf.v, vf[dblk].v, z, 0, 0, 0);
  }

#pragma unroll
  for (int dblk = 0; dblk < 4; ++dblk)
#pragma unroll
    for (int r = 0; r < 4; ++r)
      att[(size_t)(b * N + i0 + 4 * g + r) * 512 + h * 64 + dblk * 16 + c] =
          __float2bfloat16(o[dblk][r]);
}

// ---------------- launch ----------------

extern "C" void kernel_launch(void* const* d_in, const int* in_sizes, int n_in,
                              void* d_out, int out_size, void* d_ws, size_t ws_size,
                              hipStream_t stream) {
  const float* x = (const float*)d_in[0];      // [4,2048,512]
  const float* Wqkv = (const float*)d_in[1];   // [512,1536]
  const float* Wproj = (const float*)d_in[2];  // [512,512]
  const float* bproj = (const float*)d_in[3];  // [512]
  float* out = (float*)d_out;                  // [4,2048,512]
  (void)in_sizes; (void)n_in; (void)out_size; (void)ws_size;

  const int M = 8192;  // B*N
  const int C = 512;
  const int N3 = 1536;

  size_t off = 0;
  auto alloc = [&](size_t bytes) {
    void* p = (char*)d_ws + off;
    off += (bytes + 255) & ~(size_t)255;
    return p;
  };
  __hip_bfloat16* xb = (__hip_bfloat16*)alloc((size_t)M * C * 2);       // 8 MB
  __hip_bfloat16* wqkvT = (__hip_bfloat16*)alloc((size_t)N3 * C * 2);   // 1.5 MB
  __hip_bfloat16* wprojT = (__hip_bfloat16*)alloc((size_t)C * C * 2);   // 0.5 MB
  __hip_bfloat16* qkvb = (__hip_bfloat16*)alloc((size_t)M * N3 * 2);    // 25 MB
  __hip_bfloat16* attb = (__hip_bfloat16*)alloc((size_t)M * C * 2);     // 8 MB

  // fused prep: x cast (4096) + WqkvT tiles (192) + WprojT tiles (64)
  prep_kernel<<<4352, 256, 0, stream>>>(x, Wqkv, Wproj, xb, wqkvT, wprojT);

  // GEMM1: qkv = x @ Wqkv   (M=8192, N=1536, K=512) -> bf16   (768 blocks)
  gemm_bt<1, 0><<<dim3(N3 / BN, M / BM), 256, 0, stream>>>(
      xb, wqkvT, qkvb, nullptr, M, N3, C);

  // banded attention (MFMA): 4096 waves, 4 per block
  attn_mfma_kernel<<<1024, 256, 0, stream>>>(qkvb, attb);

  // GEMM2: out = att @ Wproj + bproj  (M=8192, N=512, K=512) -> fp32  (256 blocks)
  gemm_bt<0, 1><<<dim3(C / BN, M / BM), 256, 0, stream>>>(
      attb, wprojT, out, bproj, M, C, C);
}